// Round 11
// baseline (158.761 us; speedup 1.0000x reference)
//
#include <hip/hip_runtime.h>

// Problem constants
#define BB 256      // batch
#define CCH 512     // channels
#define HW 196      // 14*14 spatial
#define TT 197      // templates_b rows (196 + 1 negative)
#define TROWS 208   // padded T rows (13 * 16)
#define NFRAG (13 * 7)            // (mt, kt) fragment blocks
#define ASHORTS (NFRAG * 64 * 8)  // 46592 shorts = 93184 B

typedef __attribute__((ext_vector_type(8))) short bf16x8;
typedef __attribute__((ext_vector_type(4))) float f32x4;

__device__ __forceinline__ unsigned short f2bf(float f) {
    union { float f; unsigned u; } v; v.f = f;
    unsigned r = v.u + 0x7FFFu + ((v.u >> 16) & 1u);   // round-to-nearest-even
    return (unsigned short)(r >> 16);
}

// ---- prep: wgs 0..181 build the A-table in FRAGMENT-CONTIGUOUS order:
// A[mt][kt][lane][j] = templates_b[mt*16 + (lane&15)][kt*32 + (lane>>4)*8 + j] * tau
// (each MFMA A-operand = 1024 contiguous bytes). wg 182 computes
// gmax = max(templates_f) (center peak is inside every 14x14 window).
__global__ void prep(const float* __restrict__ tf, const float* __restrict__ tb,
                     float* __restrict__ wsf, unsigned short* __restrict__ tb_bf) {
    if (blockIdx.x < 182) {
        int i = blockIdx.x * 256 + threadIdx.x;     // 182*256 == 46592 exactly
        int frag = i >> 9;                          // 512 shorts per (mt,kt) block
        int s    = i & 511;
        int mt = frag / 7, kt = frag % 7;
        int lane = s >> 3, j = s & 7;
        int r = mt * 16 + (lane & 15);
        int k = kt * 32 + (lane >> 4) * 8 + j;
        const float tau = 0.5f / 196.0f;
        float v = (r < TT && k < HW) ? tb[r * HW + k] * tau : 0.0f;
        tb_bf[i] = f2bf(v);
    } else {
        __shared__ float red[256];
        float m = -1e30f;
        for (int i = threadIdx.x; i < HW * HW; i += 256) m = fmaxf(m, tf[i]);
        red[threadIdx.x] = m;
        __syncthreads();
        for (int s = 128; s > 0; s >>= 1) {
            if (threadIdx.x < s) red[threadIdx.x] = fmaxf(red[threadIdx.x], red[threadIdx.x + s]);
            __syncthreads();
        }
        if (threadIdx.x == 0) wsf[0] = red[0];
    }
}

// ---- K1: pure streaming mask. Thread-quad per (b,c) row, rows consecutive
// in memory (wave = 16 consecutive rows = 12.5KB dense window; each instr's
// quad covers a full 64B line). (256,4) -> 64 VGPRs: all 13 x-loads issue
// BATCHED into xv[13] (52 regs), retained through the mask phase.
extern "C" __global__ __launch_bounds__(256, 4)
void k_stream(const float* __restrict__ x, const float* __restrict__ tf,
              const float* __restrict__ wsf,
              float* __restrict__ xm_out, float* __restrict__ mask_out)
{
    const int tid = threadIdx.x;
    const int row = blockIdx.x * 64 + (tid >> 2);   // row = b*512 + c
    const int q   = tid & 3;
    const int nch = (q == 0) ? 13 : 12;             // q=0 also takes chunk 48
    const float rg = 1.0f / wsf[0];

    const size_t rowoff = (size_t)row * HW;
    const float* xrow = x + rowoff;

    // ---- batched loads + argmax (k ascends per lane -> strict > keeps first)
    f32x4 xv[13];
    #pragma unroll
    for (int j = 0; j < 13; ++j)
        if (j < nch) xv[j] = *(const f32x4*)(xrow + (q + 4 * j) * 4);

    float bv = -__builtin_inff(); int bi = 0;
    #pragma unroll
    for (int j = 0; j < 13; ++j) if (j < nch) {
        const int k0 = (q + 4 * j) * 4;
        #pragma unroll
        for (int e = 0; e < 4; ++e) {
            float v = xv[j][e];
            if (v > bv) { bv = v; bi = k0 + e; }
        }
    }
    #pragma unroll
    for (int m = 1; m <= 2; m <<= 1) {
        float ov = __shfl_xor(bv, m, 64);
        int   oi = __shfl_xor(bi, m, 64);
        if (ov > bv || (ov == bv && oi < bi)) { bv = ov; bi = oi; }
    }

    // ---- mask + stores (xv retained, no re-read)
    const float* selrow = tf + (size_t)bi * HW;
    float* xmrow = xm_out + rowoff;
    float* mkrow = mask_out + rowoff;

    #pragma unroll
    for (int j = 0; j < 13; ++j) if (j < nch) {
        const int k0 = (q + 4 * j) * 4;
        f32x4 sel = *(const f32x4*)(selrow + k0);
        f32x4 mk, xm;
        #pragma unroll
        for (int e = 0; e < 4; ++e) {
            float m = fmaxf(sel[e] * rg - 0.2f, 0.0f) * 5.0f;
            mk[e] = m;
            xm[e] = xv[j][e] * m;
        }
        *(f32x4*)(xmrow + k0) = xm;
        *(f32x4*)(mkrow + k0) = mk;
    }
}

// ---- K2: per-channel GEMM + softmax + MI loss (round-10 fused_one minus
// streaming). One wg (1024 thr, 16 waves) per channel. B-frags packed from
// xm fp32 (L3-hot, bit-identical to round-10's in-register values). A-table
// staged to LDS in fragment-contiguous order -> conflict-free ds_read_b128.
extern "C" __global__ __launch_bounds__(1024)
void k_gemm_loss(const float* __restrict__ xm, const float* __restrict__ pT,
                 const unsigned short* __restrict__ tb_bf,
                 float* __restrict__ loss_out)
{
    extern __shared__ char smem[];
    unsigned short* Alds = (unsigned short*)smem;                 // [91][512] bf16 frags
    float* s_part = (float*)(smem + ASHORTS * 2);                 // [16][208]
    float* rAs    = s_part + 16 * TROWS;                          // [208]
    float* pTs    = rAs + TROWS;                                  // [208]
    float* red    = pTs + TROWS;                                  // [16]

    const int c    = blockIdx.x;
    const int tid  = threadIdx.x;
    const int lane = tid & 63;
    const int w    = tid >> 6;
    const int l15  = lane & 15, lg = lane >> 4;

    // ---- stage A-table into LDS (5824 x 16B chunks over 1024 threads)
    {
        const f32x4* src = (const f32x4*)tb_bf;
        f32x4* dst = (f32x4*)Alds;
        #pragma unroll
        for (int it = 0; it < 6; ++it) {
            int idx = tid + it * 1024;
            if (idx < ASHORTS / 8) dst[idx] = src[idx];
        }
    }
    if (tid < TROWS) pTs[tid] = (tid < TT) ? pT[tid] : 0.0f;

    const int b = w * 16 + l15;
    const float* xrow = xm + ((size_t)b * CCH + c) * HW;

    // ---- B-frag pack straight from xm (no retention)
    bf16x8 fr[7];
    #pragma unroll
    for (int kt = 0; kt < 6; ++kt) {
        f32x4 u0 = *(const f32x4*)(xrow + kt * 32 + lg * 8);
        f32x4 u1 = *(const f32x4*)(xrow + kt * 32 + lg * 8 + 4);
        #pragma unroll
        for (int e = 0; e < 4; ++e) {
            fr[kt][e]     = (short)f2bf(u0[e]);
            fr[kt][e + 4] = (short)f2bf(u1[e]);
        }
    }
    fr[6] = (bf16x8){0, 0, 0, 0, 0, 0, 0, 0};
    if (lg == 0) {
        f32x4 u0 = *(const f32x4*)(xrow + 192);
        #pragma unroll
        for (int e = 0; e < 4; ++e) fr[6][e] = (short)f2bf(u0[e]);
    }

    __syncthreads();   // A-table staged -> visible to all waves

    // ---- GEMM: tr[t = mt*16+lg*4+e][b = w*16+l15]; A-frags are contiguous
    // 1024B LDS blocks: addr = (mt*7+kt)*1024B + lane*16B (seq, 0-conflict)
    f32x4 acc[13];
    #pragma unroll
    for (int mt = 0; mt < 13; ++mt) acc[mt] = (f32x4){0.f, 0.f, 0.f, 0.f};

    const unsigned short* Abase = Alds + lane * 8;
    #pragma unroll
    for (int kt = 0; kt < 7; ++kt) {
        const bf16x8 bfrag = fr[kt];
        #pragma unroll
        for (int mt = 0; mt < 13; ++mt) {
            bf16x8 afrag = *(const bf16x8*)(Abase + (mt * 7 + kt) * 512);
            acc[mt] = __builtin_amdgcn_mfma_f32_16x16x32_bf16(afrag, bfrag, acc[mt], 0, 0, 0);
        }
    }

    // ---- Phase A: exp in-register, col-sum over this wave's 16 b, cross-wave via LDS
    float* sp = s_part + w * TROWS;
    #pragma unroll
    for (int mt = 0; mt < 13; ++mt) {
        #pragma unroll
        for (int e = 0; e < 4; ++e) acc[mt][e] = __expf(acc[mt][e]);
        f32x4 s = acc[mt];
        #pragma unroll
        for (int m = 1; m <= 8; m <<= 1) {
            #pragma unroll
            for (int e = 0; e < 4; ++e) s[e] += __shfl_xor(s[e], m, 64);
        }
        if (l15 == 0) *(f32x4*)(sp + mt * 16 + lg * 4) = s;
    }
    __syncthreads();
    if (tid < TROWS) {
        float s = 0.f;
        #pragma unroll
        for (int w2 = 0; w2 < 16; ++w2) s += s_part[w2 * TROWS + tid];
        rAs[tid] = 1.0f / s;
    }
    __syncthreads();

    // ---- Phase B: p = exp*rA, px[b] = sum_t pT*p
    float px = 0.f;
    #pragma unroll
    for (int mt = 0; mt < 13; ++mt) {
        const int t0 = mt * 16 + lg * 4;
        f32x4 ra = *(const f32x4*)(rAs + t0);
        f32x4 pt = *(const f32x4*)(pTs + t0);
        #pragma unroll
        for (int e = 0; e < 4; ++e) {
            float p = acc[mt][e] * ra[e];
            acc[mt][e] = p;
            px += pt[e] * p;
        }
    }
    px += __shfl_xor(px, 16, 64);
    px += __shfl_xor(px, 32, 64);
    const float rpx = 1.0f / px;

    // ---- Phase C: loss partial = sum_t pT * p * log(p/px)
    float part = 0.f;
    #pragma unroll
    for (int mt = 0; mt < 13; ++mt) {
        const int t0 = mt * 16 + lg * 4;
        f32x4 pt = *(const f32x4*)(pTs + t0);
        #pragma unroll
        for (int e = 0; e < 4; ++e) {
            float p = acc[mt][e];
            part += pt[e] * p * __logf(p * rpx);
        }
    }
    #pragma unroll
    for (int off = 32; off >= 1; off >>= 1) part += __shfl_xor(part, off, 64);
    if (lane == 0) red[w] = part;
    __syncthreads();
    if (tid == 0) {
        float s = 0.f;
        #pragma unroll
        for (int w2 = 0; w2 < 16; ++w2) s += red[w2];
        loss_out[c] = -s;
    }
}

extern "C" void kernel_launch(void* const* d_in, const int* in_sizes, int n_in,
                              void* d_out, int out_size, void* d_ws, size_t ws_size,
                              hipStream_t stream) {
    const float* x  = (const float*)d_in[0];
    const float* tf = (const float*)d_in[1];
    const float* tb = (const float*)d_in[2];
    const float* pT = (const float*)d_in[3];

    const size_t NOUT = (size_t)BB * CCH * HW;
    float* xm_out = (float*)d_out;
    float* mk_out = xm_out + NOUT;
    float* ls_out = mk_out + NOUT;

    float* wsf = (float*)d_ws;
    unsigned short* tb_bf = (unsigned short*)((char*)d_ws + 64);   // 93184 B

    prep<<<183, 256, 0, stream>>>(tf, tb, wsf, tb_bf);
    k_stream<<<2048, 256, 0, stream>>>(x, tf, wsf, xm_out, mk_out);

    const size_t SMEM = (size_t)ASHORTS * 2              // A-table: 93184
                      + 16 * TROWS * 4                   // s_part: 13312
                      + TROWS * 4 + TROWS * 4 + 16 * 4;  // rAs + pTs + red
    hipFuncSetAttribute((const void*)k_gemm_loss, hipFuncAttributeMaxDynamicSharedMemorySize, (int)SMEM);
    k_gemm_loss<<<dim3(CCH), dim3(1024), SMEM, stream>>>(xm_out, pT, tb_bf, ls_out);
}

// Round 12
// 144.220 us; speedup vs baseline: 1.1008x; 1.1008x over previous
//
#include <hip/hip_runtime.h>

// Problem constants
#define BB 256      // batch
#define CCH 512     // channels
#define HW 196      // 14*14 spatial
#define TT 197      // templates_b rows (196 + 1 negative)
#define TROWS 208   // padded T rows (13 * 16)
#define NFRAG (13 * 7)            // (mt, kt) fragment blocks
#define ASHORTS (NFRAG * 64 * 8)  // 46592 shorts = 93184 B
#define H1FRAG (7 * 7)            // half 1: mt 0..6
#define H2FRAG (6 * 7)            // half 2: mt 7..12
#define H1SHORTS (H1FRAG * 512)   // 25088 shorts = 50176 B
#define H2SHORTS (H2FRAG * 512)   // 21504 shorts = 43008 B

typedef __attribute__((ext_vector_type(8))) short bf16x8;
typedef __attribute__((ext_vector_type(4))) float f32x4;

__device__ __forceinline__ unsigned short f2bf(float f) {
    union { float f; unsigned u; } v; v.f = f;
    unsigned r = v.u + 0x7FFFu + ((v.u >> 16) & 1u);   // round-to-nearest-even
    return (unsigned short)(r >> 16);
}

// ---- prep: wgs 0..181 build the A-table in FRAGMENT-CONTIGUOUS order:
// A[mt][kt][lane][j] = templates_b[mt*16 + (lane&15)][kt*32 + (lane>>4)*8 + j] * tau
// (each MFMA A-operand = 1024 contiguous bytes). wg 182 computes
// gmax = max(templates_f) (center peak is inside every 14x14 window).
__global__ void prep(const float* __restrict__ tf, const float* __restrict__ tb,
                     float* __restrict__ wsf, unsigned short* __restrict__ tb_bf) {
    if (blockIdx.x < 182) {
        int i = blockIdx.x * 256 + threadIdx.x;     // 182*256 == 46592 exactly
        int frag = i >> 9;                          // 512 shorts per (mt,kt) block
        int s    = i & 511;
        int mt = frag / 7, kt = frag % 7;
        int lane = s >> 3, j = s & 7;
        int r = mt * 16 + (lane & 15);
        int k = kt * 32 + (lane >> 4) * 8 + j;
        const float tau = 0.5f / 196.0f;
        float v = (r < TT && k < HW) ? tb[r * HW + k] * tau : 0.0f;
        tb_bf[i] = f2bf(v);
    } else {
        __shared__ float red[256];
        float m = -1e30f;
        for (int i = threadIdx.x; i < HW * HW; i += 256) m = fmaxf(m, tf[i]);
        red[threadIdx.x] = m;
        __syncthreads();
        for (int s = 128; s > 0; s >>= 1) {
            if (threadIdx.x < s) red[threadIdx.x] = fmaxf(red[threadIdx.x], red[threadIdx.x + s]);
            __syncthreads();
        }
        if (threadIdx.x == 0) wsf[0] = red[0];
    }
}

// ---- fused kernel: one wg (1024 thr, 16 waves) per channel.
// Round-10 structure (register-staged B-frags, fragment-contiguous LDS A,
// in-register softmax/loss) BUT the A-table is staged in TWO HALVES into a
// 50KB buffer -> total LDS 63.7KB -> 2 wgs/CU: one wg's latency-bound stream
// phase overlaps the other's GEMM/softmax, and 32 waves/CU double the
// outstanding-load pool during streaming.
extern "C" __global__ __launch_bounds__(1024)
void fused_one(const float* __restrict__ x, const float* __restrict__ tf,
               const float* __restrict__ pT, const unsigned short* __restrict__ tb_bf,
               const float* __restrict__ wsf,
               float* __restrict__ xm_out, float* __restrict__ mask_out,
               float* __restrict__ loss_out)
{
    extern __shared__ char smem[];
    unsigned short* Alds = (unsigned short*)smem;                 // [49][512] bf16 frags (half buffer)
    float* s_part = (float*)(smem + H1SHORTS * 2);                // [16][208]
    float* rAs    = s_part + 16 * TROWS;                          // [208]
    float* pTs    = rAs + TROWS;                                  // [208]
    float* red    = pTs + TROWS;                                  // [16]

    const int c    = blockIdx.x;
    const int tid  = threadIdx.x;
    const int lane = tid & 63;
    const int w    = tid >> 6;
    const int l15  = lane & 15, lg = lane >> 4;
    const float rg = 1.0f / wsf[0];

    // ---- stage A-table HALF 1 (mt 0..6): 3136 x 16B chunks over 1024 threads
    {
        const f32x4* src = (const f32x4*)tb_bf;
        f32x4* dst = (f32x4*)Alds;
        #pragma unroll
        for (int it = 0; it < 4; ++it) {
            int idx = tid + it * 1024;
            if (idx < H1SHORTS / 8) dst[idx] = src[idx];
        }
    }
    if (tid < TROWS) pTs[tid] = (tid < TT) ? pT[tid] : 0.0f;

    const int b = w * 16 + l15;
    const size_t rowoff = ((size_t)b * CCH + c) * HW;
    const float* xrow = x + rowoff;

    // ---- load this lane's 12 (13 for lg==0) chunks of its row
    f32x4 u[13];
    #pragma unroll
    for (int kt = 0; kt < 6; ++kt) {
        u[2 * kt]     = *(const f32x4*)(xrow + kt * 32 + lg * 8);
        u[2 * kt + 1] = *(const f32x4*)(xrow + kt * 32 + lg * 8 + 4);
    }
    if (lg == 0) u[12] = *(const f32x4*)(xrow + 192);
    else         u[12] = (f32x4){-__builtin_inff(), -__builtin_inff(),
                                 -__builtin_inff(), -__builtin_inff()};

    // ---- argmax (k ascends within each lane's scan -> strict > keeps first)
    float bv = -__builtin_inff(); int bi = 0;
    #pragma unroll
    for (int j = 0; j < 13; ++j) {
        const int k0 = (j < 12) ? (((j >> 1) * 8 + lg * 2 + (j & 1)) * 4) : 192;
        #pragma unroll
        for (int e = 0; e < 4; ++e) {
            float v = u[j][e];
            if (v > bv) { bv = v; bi = k0 + e; }
        }
    }
    #pragma unroll
    for (int m = 16; m <= 32; m <<= 1) {   // reduce over lg (lanes l15+16g)
        float ov = __shfl_xor(bv, m, 64);
        int   oi = __shfl_xor(bi, m, 64);
        if (ov > bv || (ov == bv && oi < bi)) { bv = ov; bi = oi; }
    }

    // ---- mask, outputs, and B-frag pack (u dies into fr)
    const float* selrow = tf + (size_t)bi * HW;
    float* xmrow = xm_out + rowoff;
    float* mkrow = mask_out + rowoff;
    bf16x8 fr[7];

    #pragma unroll
    for (int kt = 0; kt < 6; ++kt) {
        #pragma unroll
        for (int h = 0; h < 2; ++h) {
            const int k0 = kt * 32 + lg * 8 + h * 4;
            f32x4 sel = *(const f32x4*)(selrow + k0);
            f32x4 mk, xm;
            #pragma unroll
            for (int e = 0; e < 4; ++e) {
                float m = fmaxf(sel[e] * rg - 0.2f, 0.0f) * 5.0f;
                mk[e] = m;
                xm[e] = u[2 * kt + h][e] * m;
            }
            *(f32x4*)(xmrow + k0) = xm;
            *(f32x4*)(mkrow + k0) = mk;
            #pragma unroll
            for (int e = 0; e < 4; ++e) fr[kt][h * 4 + e] = (short)f2bf(xm[e]);
        }
    }
    {   // kt=6: only lg==0 has real data (floats 192..195); rest zero-pad
        fr[6] = (bf16x8){0, 0, 0, 0, 0, 0, 0, 0};
        if (lg == 0) {
            f32x4 sel = *(const f32x4*)(selrow + 192);
            f32x4 mk, xm;
            #pragma unroll
            for (int e = 0; e < 4; ++e) {
                float m = fmaxf(sel[e] * rg - 0.2f, 0.0f) * 5.0f;
                mk[e] = m;
                xm[e] = u[12][e] * m;
            }
            *(f32x4*)(xmrow + 192) = xm;
            *(f32x4*)(mkrow + 192) = mk;
            #pragma unroll
            for (int e = 0; e < 4; ++e) fr[6][e] = (short)f2bf(xm[e]);
        }
    }

    __syncthreads();   // A half 1 staged -> visible to all waves

    // ---- GEMM pass 1: mt 0..6 (A-frags = contiguous 1024B LDS blocks)
    f32x4 acc[13];
    #pragma unroll
    for (int mt = 0; mt < 13; ++mt) acc[mt] = (f32x4){0.f, 0.f, 0.f, 0.f};

    const unsigned short* Abase = Alds + lane * 8;
    #pragma unroll
    for (int kt = 0; kt < 7; ++kt) {
        const bf16x8 bfrag = fr[kt];
        #pragma unroll
        for (int mt = 0; mt < 7; ++mt) {
            bf16x8 afrag = *(const bf16x8*)(Abase + (mt * 7 + kt) * 512);
            acc[mt] = __builtin_amdgcn_mfma_f32_16x16x32_bf16(afrag, bfrag, acc[mt], 0, 0, 0);
        }
    }

    __syncthreads();   // all waves done reading half 1

    // ---- restage A-table HALF 2 (mt 7..12): 2688 x 16B chunks
    {
        const f32x4* src = (const f32x4*)(tb_bf + H1SHORTS);
        f32x4* dst = (f32x4*)Alds;
        #pragma unroll
        for (int it = 0; it < 3; ++it) {
            int idx = tid + it * 1024;
            if (idx < H2SHORTS / 8) dst[idx] = src[idx];
        }
    }
    __syncthreads();   // half 2 staged

    // ---- GEMM pass 2: mt 7..12
    #pragma unroll
    for (int kt = 0; kt < 7; ++kt) {
        const bf16x8 bfrag = fr[kt];
        #pragma unroll
        for (int mt = 7; mt < 13; ++mt) {
            bf16x8 afrag = *(const bf16x8*)(Abase + ((mt - 7) * 7 + kt) * 512);
            acc[mt] = __builtin_amdgcn_mfma_f32_16x16x32_bf16(afrag, bfrag, acc[mt], 0, 0, 0);
        }
    }

    // ---- Phase A: exp in-register, col-sum over this wave's 16 b, cross-wave via LDS
    float* sp = s_part + w * TROWS;
    #pragma unroll
    for (int mt = 0; mt < 13; ++mt) {
        #pragma unroll
        for (int e = 0; e < 4; ++e) acc[mt][e] = __expf(acc[mt][e]);
        f32x4 s = acc[mt];
        #pragma unroll
        for (int m = 1; m <= 8; m <<= 1) {
            #pragma unroll
            for (int e = 0; e < 4; ++e) s[e] += __shfl_xor(s[e], m, 64);
        }
        if (l15 == 0) *(f32x4*)(sp + mt * 16 + lg * 4) = s;
    }
    __syncthreads();
    if (tid < TROWS) {
        float s = 0.f;
        #pragma unroll
        for (int w2 = 0; w2 < 16; ++w2) s += s_part[w2 * TROWS + tid];
        rAs[tid] = 1.0f / s;
    }
    __syncthreads();

    // ---- Phase B: p = exp*rA, px[b] = sum_t pT*p
    float px = 0.f;
    #pragma unroll
    for (int mt = 0; mt < 13; ++mt) {
        const int t0 = mt * 16 + lg * 4;
        f32x4 ra = *(const f32x4*)(rAs + t0);
        f32x4 pt = *(const f32x4*)(pTs + t0);
        #pragma unroll
        for (int e = 0; e < 4; ++e) {
            float p = acc[mt][e] * ra[e];
            acc[mt][e] = p;
            px += pt[e] * p;
        }
    }
    px += __shfl_xor(px, 16, 64);
    px += __shfl_xor(px, 32, 64);
    const float rpx = 1.0f / px;

    // ---- Phase C: loss partial = sum_t pT * p * log(p/px)
    float part = 0.f;
    #pragma unroll
    for (int mt = 0; mt < 13; ++mt) {
        const int t0 = mt * 16 + lg * 4;
        f32x4 pt = *(const f32x4*)(pTs + t0);
        #pragma unroll
        for (int e = 0; e < 4; ++e) {
            float p = acc[mt][e];
            part += pt[e] * p * __logf(p * rpx);
        }
    }
    #pragma unroll
    for (int off = 32; off >= 1; off >>= 1) part += __shfl_xor(part, off, 64);
    if (lane == 0) red[w] = part;
    __syncthreads();
    if (tid == 0) {
        float s = 0.f;
        #pragma unroll
        for (int w2 = 0; w2 < 16; ++w2) s += red[w2];
        loss_out[c] = -s;
    }
}

extern "C" void kernel_launch(void* const* d_in, const int* in_sizes, int n_in,
                              void* d_out, int out_size, void* d_ws, size_t ws_size,
                              hipStream_t stream) {
    const float* x  = (const float*)d_in[0];
    const float* tf = (const float*)d_in[1];
    const float* tb = (const float*)d_in[2];
    const float* pT = (const float*)d_in[3];

    const size_t NOUT = (size_t)BB * CCH * HW;
    float* xm_out = (float*)d_out;
    float* mk_out = xm_out + NOUT;
    float* ls_out = mk_out + NOUT;

    float* wsf = (float*)d_ws;
    unsigned short* tb_bf = (unsigned short*)((char*)d_ws + 64);   // 93184 B

    prep<<<183, 256, 0, stream>>>(tf, tb, wsf, tb_bf);

    const size_t SMEM = (size_t)H1SHORTS * 2             // A half buffer: 50176
                      + 16 * TROWS * 4                   // s_part: 13312
                      + TROWS * 4 + TROWS * 4 + 16 * 4;  // rAs + pTs + red
    hipFuncSetAttribute((const void*)fused_one, hipFuncAttributeMaxDynamicSharedMemorySize, (int)SMEM);
    fused_one<<<dim3(CCH), dim3(1024), SMEM, stream>>>(x, tf, pT, tb_bf, wsf,
                                                       xm_out, mk_out, ls_out);
}